// Round 15
// baseline (256.584 us; speedup 1.0000x reference)
//
#include <hip/hip_runtime.h>
#include <cmath>
#include <cfloat>

namespace {

constexpr int kB   = 1024;
constexpr int kL   = 64;
constexpr int kHid = 512;
constexpr int kLow = 20;
constexpr int kLM1 = 63;              // L-1
constexpr int kRowElems = kL * kLow;  // 1280 floats per batch row of h0/c0

typedef float v2f __attribute__((ext_vector_type(2)));

__device__ __forceinline__ float fsig(float x) {
  return __builtin_amdgcn_rcpf(1.0f + __expf(-x));
}
__device__ __forceinline__ float ftanhf(float x) {
  return 1.0f - 2.0f * __builtin_amdgcn_rcpf(1.0f + __expf(2.0f * x));
}
__device__ __forceinline__ int rdl_i(int v, int l) {
  return __builtin_amdgcn_readlane(v, l);
}
__device__ __forceinline__ float rdl_f(float v, int l) {
  return __int_as_float(__builtin_amdgcn_readlane(__float_as_int(v), l));
}

// DPP helpers (ctrl must be a literal -> macros).
#define DPPI(v, ctrl) __builtin_amdgcn_update_dpp((v), (v), (ctrl), 0xF, 0xF, false)
#define DPPF(v, ctrl) __int_as_float(DPPI(__float_as_int(v), (ctrl)))
#define DPPF0(v, ctrl)                                                        \
  __int_as_float(__builtin_amdgcn_update_dpp(0, __float_as_int(v), (ctrl),    \
                                             0xF, 0xF, true))
#define UMAX_STAGE(CTRL)                                                      \
  {                                                                           \
    const unsigned o_ = (unsigned)DPPI((int)m, CTRL);                         \
    m = (m > o_) ? m : o_;                                                    \
  }

// packed 2xf32 FMA
#define PKFMA(ACC, X, W)                                                      \
  asm("v_pk_fma_f32 %0, %1, %2, %0" : "+v"(ACC) : "v"(X), "v"(W))

// logit: sum over each 32-lane half; totals land in lanes 31 and 63.
#define LOGIT_REDUCE(PR_)                                                     \
  {                                                                           \
    PR_ += DPPF0(PR_, 0xB1);                                                  \
    PR_ += DPPF0(PR_, 0x4E);                                                  \
    PR_ += DPPF0(PR_, 0x141);                                                 \
    PR_ += DPPF0(PR_, 0x140);                                                 \
    PR_ += DPPF0(PR_, 0x142);                                                 \
  }

// ---------------------------------------------------------------------------
// Phase 1: h0/c0 = X @ W_reduce + b. R15: T14 async-STAGE split — chunk ch+1
// is loaded into REGISTERS while chunk ch computes; regs -> LDS after the
// next barrier. Same math/order as R12 (absmax must be bit-identical).
// VGPR ~61 (<= 64 step) keeps 6 blocks/CU.
// ---------------------------------------------------------------------------
__global__ __launch_bounds__(256, 6)
void reduce_kernel(const float* __restrict__ Xh, const float* __restrict__ Xc,
                   const float* __restrict__ W, const float* __restrict__ bv,
                   float* __restrict__ H0, float* __restrict__ C0) {
  __shared__ float xs[5184];       // 64 rows x pitch 65; reused as scratch
  __shared__ float wsm[64 * 20];   // W chunk

  const int bid = blockIdx.x;
  const float* __restrict__ X = (bid < kB) ? Xh : Xc;
  float* __restrict__ O       = (bid < kB) ? H0 : C0;
  const int b = bid & (kB - 1);
  X += (size_t)b * kL * kHid;
  O += (size_t)b * kRowElems;

  const int tid  = threadIdx.x;
  const int wave = tid >> 6;
  const int lane = tid & 63;

  float acc[20];
#pragma unroll
  for (int d = 0; d < 20; ++d) acc[d] = 0.0f;

  // ---- prologue: prefetch chunk 0 into registers ----
  float4 xr[4];
  float  wr5[5];
#pragma unroll
  for (int r = 0; r < 4; ++r) {
    int f   = r * 256 + tid;
    int row = f >> 4;
    int c4  = (f & 15) << 2;
    xr[r] = *(const float4*)(X + row * kHid + c4);
  }
#pragma unroll
  for (int r = 0; r < 5; ++r) wr5[r] = W[r * 256 + tid];

#pragma unroll 1
  for (int ch = 0; ch < 8; ++ch) {
    __syncthreads();  // all reads of xs/wsm for chunk ch-1 complete
    // stage prefetched chunk ch: regs -> LDS
#pragma unroll
    for (int r = 0; r < 4; ++r) {
      int f   = r * 256 + tid;
      int row = f >> 4;
      int c4  = (f & 15) << 2;
      *(float4*)(xs + row * 65 + c4) = xr[r];
    }
#pragma unroll
    for (int r = 0; r < 5; ++r) wsm[r * 256 + tid] = wr5[r];
    __syncthreads();  // publish

    // issue chunk ch+1 loads (latency hides under the compute below)
    if (ch < 7) {
#pragma unroll
      for (int r = 0; r < 4; ++r) {
        int f   = r * 256 + tid;
        int row = f >> 4;
        int c4  = (f & 15) << 2;
        xr[r] = *(const float4*)(X + row * kHid + (ch + 1) * 64 + c4);
      }
#pragma unroll
      for (int r = 0; r < 5; ++r) wr5[r] = W[(ch + 1) * 1280 + r * 256 + tid];
    }

    // compute: lane = token, wave covers k in [wave*16, wave*16+16)
#pragma unroll
    for (int kk = 0; kk < 16; ++kk) {
      int k = wave * 16 + kk;
      float x = xs[lane * 65 + k];
      const float4* wp = (const float4*)(wsm + k * 20);
      float4 w0 = wp[0], w1 = wp[1], w2 = wp[2], w3 = wp[3], w4 = wp[4];
      acc[0]  = fmaf(x, w0.x, acc[0]);  acc[1]  = fmaf(x, w0.y, acc[1]);
      acc[2]  = fmaf(x, w0.z, acc[2]);  acc[3]  = fmaf(x, w0.w, acc[3]);
      acc[4]  = fmaf(x, w1.x, acc[4]);  acc[5]  = fmaf(x, w1.y, acc[5]);
      acc[6]  = fmaf(x, w1.z, acc[6]);  acc[7]  = fmaf(x, w1.w, acc[7]);
      acc[8]  = fmaf(x, w2.x, acc[8]);  acc[9]  = fmaf(x, w2.y, acc[9]);
      acc[10] = fmaf(x, w2.z, acc[10]); acc[11] = fmaf(x, w2.w, acc[11]);
      acc[12] = fmaf(x, w3.x, acc[12]); acc[13] = fmaf(x, w3.y, acc[13]);
      acc[14] = fmaf(x, w3.z, acc[14]); acc[15] = fmaf(x, w3.w, acc[15]);
      acc[16] = fmaf(x, w4.x, acc[16]); acc[17] = fmaf(x, w4.y, acc[17]);
      acc[18] = fmaf(x, w4.z, acc[18]); acc[19] = fmaf(x, w4.w, acc[19]);
    }
  }

  __syncthreads();
  float* red = xs;  // 4*64*20 = 5120 floats scratch
#pragma unroll
  for (int d = 0; d < 20; ++d) red[wave * 1280 + lane * 20 + d] = acc[d];
  __syncthreads();
#pragma unroll
  for (int r = 0; r < 5; ++r) {
    int f = r * 256 + tid;
    float s = (red[f] + red[1280 + f]) + (red[2560 + f] + red[3840 + f]);
    O[f] = s + bv[f % 20];
  }
}

// LDS-weight TreeLSTM eval of one (pair, dim) unit — init pass only.
#define EVAL_UNIT(A_, B2_, PS_, DD_, HN_)                                     \
  {                                                                           \
    float ai = bcs[DD_], af = bcs[20 + DD_], ag = bcs[40 + DD_],              \
          au = bcs[60 + DD_], ao = bcs[80 + DD_];                             \
    const int xa_ = (A_)*20, xb_ = (B2_)*20, wr_ = (DD_)*44;                  \
    _Pragma("unroll")                                                         \
    for (int kq = 0; kq < 10; ++kq) {                                         \
      const float4 xq = (kq < 5)                                              \
          ? *(const float4*)(h_state + xa_ + kq * 4)                          \
          : *(const float4*)(h_state + xb_ + (kq - 5) * 4);                   \
      const float4 wi = *(const float4*)(Wt + wr_ + kq * 4);                  \
      const float4 wf = *(const float4*)(Wt + 880  + wr_ + kq * 4);           \
      const float4 wg = *(const float4*)(Wt + 1760 + wr_ + kq * 4);           \
      const float4 wu = *(const float4*)(Wt + 2640 + wr_ + kq * 4);           \
      const float4 wo = *(const float4*)(Wt + 3520 + wr_ + kq * 4);           \
      ai = fmaf(xq.x, wi.x, ai); ai = fmaf(xq.y, wi.y, ai);                   \
      ai = fmaf(xq.z, wi.z, ai); ai = fmaf(xq.w, wi.w, ai);                   \
      af = fmaf(xq.x, wf.x, af); af = fmaf(xq.y, wf.y, af);                   \
      af = fmaf(xq.z, wf.z, af); af = fmaf(xq.w, wf.w, af);                   \
      ag = fmaf(xq.x, wg.x, ag); ag = fmaf(xq.y, wg.y, ag);                   \
      ag = fmaf(xq.z, wg.z, ag); ag = fmaf(xq.w, wg.w, ag);                   \
      au = fmaf(xq.x, wu.x, au); au = fmaf(xq.y, wu.y, au);                   \
      au = fmaf(xq.z, wu.z, au); au = fmaf(xq.w, wu.w, au);                   \
      ao = fmaf(xq.x, wo.x, ao); ao = fmaf(xq.y, wo.y, ao);                   \
      ao = fmaf(xq.z, wo.z, ao); ao = fmaf(xq.w, wo.w, ao);                   \
    }                                                                         \
    const float cl_ = c_state[(A_)*20 + (DD_)],                               \
                cr_ = c_state[(B2_)*20 + (DD_)];                              \
    const float cn_ = cl_ * fsig(af + 1.0f) + cr_ * fsig(ag + 1.0f) +         \
                      ftanhf(au) * fsig(ai);                                  \
    (HN_) = fsig(ao) * ftanhf(cn_);                                           \
    nh[(PS_)*20 + (DD_)] = (HN_);                                             \
    nc[(PS_)*20 + (DD_)] = cn_;                                               \
  }

// ---------------------------------------------------------------------------
// Phase 2 (R12, best known — byte-identical): per-row Gumbel tree pyramid,
// ONE WAVE per row. Column-split eval; hoisted eval reads; DPP argmax/shift;
// 2-deep U prefetch; merge-bypass via nh/nc.
// ---------------------------------------------------------------------------
__global__ __launch_bounds__(64, 1)
void pyramid_kernel(const float* __restrict__ H0, const float* __restrict__ C0,
                    const float* __restrict__ Wc, const float* __restrict__ bcg,
                    const float* __restrict__ query, const float* __restrict__ U,
                    const int* __restrict__ length, float* __restrict__ out) {
  __shared__ float h_state[64 * 20];
  __shared__ float c_state[64 * 20];
  __shared__ float nh[63 * 20];     // cached pair h_new, by pair SLOT
  __shared__ float nc[63 * 20];     // cached pair c_new
  __shared__ float Wt[100 * 44];    // transposed W_comp (init only)
  __shared__ float bcs[100];        // bias (init only)
  __shared__ float qvs[20];         // query (init only)
  __shared__ float sc[200];         // gate-sum scratch: [pair][100]

  const int b    = blockIdx.x;
  const int lane = threadIdx.x;     // one wave
  const int p    = lane >> 5;       // nonlin phase: pair select
  const int dd   = lane & 31;       // nonlin phase: output dim (<20 active)
  const int ddc  = dd < 20 ? dd : 19;
  int len = length[b];
  len = len < 1 ? 1 : (len > 64 ? 64 : len);

  // ---- stage ----
  {
    const float4* h4 = (const float4*)(H0 + (size_t)b * kRowElems);
    const float4* c4 = (const float4*)(C0 + (size_t)b * kRowElems);
#pragma unroll
    for (int r = 0; r < 5; ++r) {
      int f = r * 64 + lane;  // 320 float4 per array
      ((float4*)h_state)[f] = h4[f];
      ((float4*)c_state)[f] = c4[f];
    }
  }
  for (int f = lane; f < 4000; f += 64) {
    int c = f / 40, k = f - c * 40;
    Wt[c * 44 + k] = Wc[k * 100 + c];
  }
  for (int f = lane; f < 100; f += 64) bcs[f] = bcg[f];
  if (lane < 20) qvs[lane] = query[lane];

  // ---- loop weights: output-column split, straight from global ----
  const bool cact = lane < 50;
  const int  c0   = cact ? 2 * lane : 0;
  const int  c1   = c0 + 1;
  v2f Wv0[20], Wv1[20];   // [k2] = {W[2k2][c], W[2k2+1][c]}
#pragma unroll
  for (int k2 = 0; k2 < 20; ++k2) {
    Wv0[k2] = (v2f){Wc[(2 * k2) * 100 + c0], Wc[(2 * k2 + 1) * 100 + c0]};
    Wv1[k2] = (v2f){Wc[(2 * k2) * 100 + c1], Wc[(2 * k2 + 1) * 100 + c1]};
  }
  const float bb0 = bcg[c0], bb1 = bcg[c1];
  const float qv_r = query[ddc];

  // per-lane register bookkeeping (position-indexed)
  int   idx_r  = lane;
  int   pidx_r = lane;
  float lgt_r  = -FLT_MAX;

  const int col = lane < 62 ? lane : 62;
  const float u_row0 = U[b * kLM1 + col];
  float u_c = U[(size_t)1 * (kB * kLM1) + b * kLM1 + col];

  // ---- init: evaluate all 63 adjacent pairs (LDS weights, parallel) ----
#pragma unroll 1
  for (int r = 0; r < 20; ++r) {
    int uu = r * 64 + lane;
    if (uu < 1260) {
      int pp = uu / 20, d2 = uu - pp * 20;
      float hn_;
      EVAL_UNIT(pp, pp + 1, pp, d2, hn_);
      (void)hn_;
    }
  }
  if (lane < 63) {
    float s = 0.0f;
#pragma unroll
    for (int q = 0; q < 5; ++q) {
      const float4 t  = *(const float4*)(nh  + lane * 20 + q * 4);
      const float4 qv = *(const float4*)(qvs + q * 4);
      s = fmaf(t.x, qv.x, s); s = fmaf(t.y, qv.y, s);
      s = fmaf(t.z, qv.z, s); s = fmaf(t.w, qv.w, s);
    }
    lgt_r = s;
  }

  float gcur = -__logf(-__logf(u_row0 + 1e-20f) + 1e-20f);

  const int nIter = len - 1;
#pragma unroll 1
  for (int i = 0; i < nIter; ++i) {
    const int n = kL - i;  // current sequence length

    // ---- argmax via u32 sort-key + DPP (ties -> lowest index) ----
    const float zf = lgt_r + gcur;
    const unsigned ub = __float_as_uint(zf);
    unsigned key = ((int)ub < 0) ? ~ub : (ub | 0x80000000u);
    const bool valid = (lane <= n - 2) && ((i + 1 + lane) < len);
    if (!valid) key = 0u;
    unsigned m = key;
    UMAX_STAGE(0xB1);
    UMAX_STAGE(0x4E);
    UMAX_STAGE(0x141);
    UMAX_STAGE(0x140);
    UMAX_STAGE(0x142);
    UMAX_STAGE(0x143);
    const unsigned gmax = (unsigned)rdl_i((int)m, 63);
    const unsigned long long bal = __ballot(valid && (key == gmax));
    const int k = (int)(__ffsll(bal) - 1);  // wave-uniform

    // ---- issue U load for row i+2 (2-deep pipeline) ----
    float u_d = 0.0f;
    if (i + 2 <= kLM1 - 1) u_d = U[(size_t)(i + 2) * (kB * kLM1) + b * kLM1 + col];

    // ---- pre-shift lookups via readlane ----
    const int km1 = (k >= 1) ? k - 1 : 0;
    const int kp2 = (k <= n - 3) ? k + 2 : 0;
    const int tgt = rdl_i(idx_r,  k);
    const int psk = rdl_i(pidx_r, k);
    const int iA  = rdl_i(idx_r,  km1);
    const int pA  = rdl_i(pidx_r, km1);
    const int iB  = rdl_i(idx_r,  kp2);

    // ---- HOISTED eval reads (latency overlaps the VALU work below) ----
    v2f hA2[10], hT2[10], hB2[10];
#pragma unroll
    for (int q = 0; q < 5; ++q) {
      const float4 tA = *(const float4*)(h_state + iA * 20 + q * 4);
      const float4 tT = *(const float4*)(nh + psk * 20 + q * 4);
      const float4 tB = *(const float4*)(h_state + iB * 20 + q * 4);
      hA2[2*q]   = (v2f){tA.x, tA.y};  hA2[2*q+1] = (v2f){tA.z, tA.w};
      hT2[2*q]   = (v2f){tT.x, tT.y};  hT2[2*q+1] = (v2f){tT.z, tT.w};
      hB2[2*q]   = (v2f){tB.x, tB.y};  hB2[2*q+1] = (v2f){tB.z, tB.w};
    }
    const float cA_ = c_state[iA * 20 + ddc];   // pair A left c
    const float cT_ = nc[psk * 20 + ddc];       // merged node c
    const float cB_ = c_state[iB * 20 + ddc];   // pair B right c

    // ---- merge: winner's cached (h,c) -> state slot tgt (off-chain) ----
    if (lane < 20) {
      h_state[tgt * 20 + lane] = nh[psk * 20 + lane];
      c_state[tgt * 20 + lane] = nc[psk * 20 + lane];
    }

    // ---- shift position-indexed registers via DPP row_shl:1 ----
    {
      int   sI = DPPI(idx_r,  0x101);
      int   sP = DPPI(pidx_r, 0x101);
      float sL = DPPF(lgt_r,  0x101);
      const int   bi16 = rdl_i(idx_r, 16),  bi32 = rdl_i(idx_r, 32),
                  bi48 = rdl_i(idx_r, 48);
      const int   bp16 = rdl_i(pidx_r, 16), bp32 = rdl_i(pidx_r, 32),
                  bp48 = rdl_i(pidx_r, 48);
      const float bl16 = rdl_f(lgt_r, 16),  bl32 = rdl_f(lgt_r, 32),
                  bl48 = rdl_f(lgt_r, 48);
      if (lane == 15) { sI = bi16; sP = bp16; sL = bl16; }
      if (lane == 31) { sI = bi32; sP = bp32; sL = bl32; }
      if (lane == 47) { sI = bi48; sP = bp48; sL = bl48; }
      const bool doI = (lane >= k + 1) && (lane <= n - 2);
      const bool doP = (lane >= k + 1) && (lane <= n - 3);
      if (doI) idx_r = sI;
      if (doP) { pidx_r = sP; lgt_r = sL; }
    }

    // ---- evaluate both candidate pairs: column-split full-K dots ----
    if (i < len - 2) {
      const bool hasA = (k >= 1);
      const bool hasB = (k <= n - 3);

      // pair A x = [hA | hT], pair B x = [hT | hB]; 4 indep chains
      v2f aA0 = (v2f){0.f, 0.f}, aA1 = aA0, aB0 = aA0, aB1 = aA0;
#pragma unroll
      for (int k2 = 0; k2 < 10; ++k2) {
        PKFMA(aA0, hA2[k2], Wv0[k2]);
        PKFMA(aA1, hA2[k2], Wv1[k2]);
        PKFMA(aB0, hT2[k2], Wv0[k2]);
        PKFMA(aB1, hT2[k2], Wv1[k2]);
      }
#pragma unroll
      for (int k2 = 10; k2 < 20; ++k2) {
        PKFMA(aA0, hT2[k2 - 10], Wv0[k2]);
        PKFMA(aA1, hT2[k2 - 10], Wv1[k2]);
        PKFMA(aB0, hB2[k2 - 10], Wv0[k2]);
        PKFMA(aB1, hB2[k2 - 10], Wv1[k2]);
      }

      // gate sums (+bias) -> LDS scratch
      if (cact) {
        *(v2f*)(sc + c0)       = (v2f){aA0[0] + aA0[1] + bb0,
                                       aA1[0] + aA1[1] + bb1};
        *(v2f*)(sc + 100 + c0) = (v2f){aB0[0] + aB0[1] + bb0,
                                       aB1[0] + aB1[1] + bb1};
      }

      // nonlinearities: lanes (p, dd<20); pair A on half0, pair B on half1
      const float* scp = sc + p * 100;
      const float i_ = scp[ddc],      fl_ = scp[20 + ddc],
                  fr_ = scp[40 + ddc], u_ = scp[60 + ddc],
                  o_ = scp[80 + ddc];
      const float cl_ = (p == 0) ? cA_ : cT_;
      const float cr_ = (p == 0) ? cT_ : cB_;
      const float cn_ = cl_ * fsig(fl_ + 1.0f) + cr_ * fsig(fr_ + 1.0f) +
                        ftanhf(u_) * fsig(i_);
      const float hn_ = fsig(o_) * ftanhf(cn_);
      const int   slot = (p == 0) ? pA : psk;
      const bool  mine = (p == 0) ? hasA : hasB;
      if (mine && dd < 20) {
        nh[slot * 20 + dd] = hn_;
        nc[slot * 20 + dd] = cn_;
      }
      float pr = (dd < 20) ? hn_ * qv_r : 0.0f;
      LOGIT_REDUCE(pr);
      const float vA = rdl_f(pr, 31);
      const float vB = rdl_f(pr, 63);
      if (hasA && lane == k - 1) lgt_r = vA;
      if (hasB && lane == k)     lgt_r = vB;
    }

    // ---- gumbel transform for row i+1 (loaded >=1 iteration ago) ----
    gcur = -__logf(-__logf(u_c + 1e-20f) + 1e-20f);
    u_c  = u_d;
  }

  const int root = rdl_i(idx_r, 0);
  if (lane < 20) {
    out[b * 20 + lane] = h_state[root * 20 + lane];
  }
}

}  // namespace

extern "C" void kernel_launch(void* const* d_in, const int* in_sizes, int n_in,
                              void* d_out, int out_size, void* d_ws, size_t ws_size,
                              hipStream_t stream) {
  const float* input_h  = (const float*)d_in[0];
  const float* input_c  = (const float*)d_in[1];
  const float* W_reduce = (const float*)d_in[2];
  const float* b_reduce = (const float*)d_in[3];
  const float* W_comp   = (const float*)d_in[4];
  const float* b_comp   = (const float*)d_in[5];
  const float* query    = (const float*)d_in[6];
  const float* u_noise  = (const float*)d_in[7];
  const int*   length   = (const int*)d_in[8];
  float* out = (float*)d_out;

  float* H0 = (float*)d_ws;
  float* C0 = H0 + (size_t)kB * kL * kLow;

  reduce_kernel<<<dim3(2 * kB), dim3(256), 0, stream>>>(
      input_h, input_c, W_reduce, b_reduce, H0, C0);
  pyramid_kernel<<<dim3(kB), dim3(64), 0, stream>>>(
      H0, C0, W_comp, b_comp, query, u_noise, length, out);
}

// Round 16
// 157.163 us; speedup vs baseline: 1.6326x; 1.6326x over previous
//
#include <hip/hip_runtime.h>
#include <cmath>
#include <cfloat>

namespace {

constexpr int kB   = 1024;
constexpr int kL   = 64;
constexpr int kHid = 512;
constexpr int kLow = 20;
constexpr int kLM1 = 63;              // L-1
constexpr int kRowElems = kL * kLow;  // 1280 floats per batch row of h0/c0

typedef float v2f __attribute__((ext_vector_type(2)));

__device__ __forceinline__ float fsig(float x) {
  return __builtin_amdgcn_rcpf(1.0f + __expf(-x));
}
__device__ __forceinline__ float ftanhf(float x) {
  return 1.0f - 2.0f * __builtin_amdgcn_rcpf(1.0f + __expf(2.0f * x));
}
__device__ __forceinline__ int rdl_i(int v, int l) {
  return __builtin_amdgcn_readlane(v, l);
}
__device__ __forceinline__ float rdl_f(float v, int l) {
  return __int_as_float(__builtin_amdgcn_readlane(__float_as_int(v), l));
}

// DPP helpers (ctrl must be a literal -> macros).
#define DPPI(v, ctrl) __builtin_amdgcn_update_dpp((v), (v), (ctrl), 0xF, 0xF, false)
#define DPPF(v, ctrl) __int_as_float(DPPI(__float_as_int(v), (ctrl)))
#define DPPF0(v, ctrl)                                                        \
  __int_as_float(__builtin_amdgcn_update_dpp(0, __float_as_int(v), (ctrl),    \
                                             0xF, 0xF, true))
#define UMAX_STAGE(CTRL)                                                      \
  {                                                                           \
    const unsigned o_ = (unsigned)DPPI((int)m, CTRL);                         \
    m = (m > o_) ? m : o_;                                                    \
  }

// packed 2xf32 FMA
#define PKFMA(ACC, X, W)                                                      \
  asm("v_pk_fma_f32 %0, %1, %2, %0" : "+v"(ACC) : "v"(X), "v"(W))

// logit: sum over each 32-lane half; totals land in lanes 31 and 63.
#define LOGIT_REDUCE(PR_)                                                     \
  {                                                                           \
    PR_ += DPPF0(PR_, 0xB1);                                                  \
    PR_ += DPPF0(PR_, 0x4E);                                                  \
    PR_ += DPPF0(PR_, 0x141);                                                 \
    PR_ += DPPF0(PR_, 0x140);                                                 \
    PR_ += DPPF0(PR_, 0x142);                                                 \
  }

// ---------------------------------------------------------------------------
// Phase 1 (R8/R12 version — known best, ~61 us timed, 70% of achievable HBM):
// h0 = input_h @ W_reduce + b ; c0 = input_c @ W_reduce + b
// 64-k chunks; X staged in LDS (coalesced float4, pitch 65); W staged in LDS
// and read as uniform-address b128 broadcasts. 25.9 KB -> 6 blocks/CU.
// (R15 lesson: reg-prefetch here spills at the 40-VGPR operating point.)
// ---------------------------------------------------------------------------
__global__ __launch_bounds__(256, 6)
void reduce_kernel(const float* __restrict__ Xh, const float* __restrict__ Xc,
                   const float* __restrict__ W, const float* __restrict__ bv,
                   float* __restrict__ H0, float* __restrict__ C0) {
  __shared__ float xs[5184];       // 64 rows x pitch 65; reused as scratch
  __shared__ float wsm[64 * 20];   // W chunk

  const int bid = blockIdx.x;
  const float* __restrict__ X = (bid < kB) ? Xh : Xc;
  float* __restrict__ O       = (bid < kB) ? H0 : C0;
  const int b = bid & (kB - 1);
  X += (size_t)b * kL * kHid;
  O += (size_t)b * kRowElems;

  const int tid  = threadIdx.x;
  const int wave = tid >> 6;
  const int lane = tid & 63;

  float acc[20];
#pragma unroll
  for (int d = 0; d < 20; ++d) acc[d] = 0.0f;

  for (int ch = 0; ch < 8; ++ch) {
    __syncthreads();
    // stage X chunk: 64 rows x 64 floats, coalesced float4
#pragma unroll
    for (int r = 0; r < 4; ++r) {
      int f   = r * 256 + tid;
      int row = f >> 4;
      int c4  = (f & 15) << 2;
      float4 v = *(const float4*)(X + row * kHid + ch * 64 + c4);
      *(float4*)(xs + row * 65 + c4) = v;
    }
    // stage W chunk: 64 x 20 contiguous
#pragma unroll
    for (int r = 0; r < 5; ++r) {
      int f = r * 256 + tid;
      wsm[f] = W[ch * 1280 + f];
    }
    __syncthreads();
    // compute: lane = token, wave covers k in [wave*16, wave*16+16)
#pragma unroll
    for (int kk = 0; kk < 16; ++kk) {
      int k = wave * 16 + kk;
      float x = xs[lane * 65 + k];
      const float4* wp = (const float4*)(wsm + k * 20);
      float4 w0 = wp[0], w1 = wp[1], w2 = wp[2], w3 = wp[3], w4 = wp[4];
      acc[0]  = fmaf(x, w0.x, acc[0]);  acc[1]  = fmaf(x, w0.y, acc[1]);
      acc[2]  = fmaf(x, w0.z, acc[2]);  acc[3]  = fmaf(x, w0.w, acc[3]);
      acc[4]  = fmaf(x, w1.x, acc[4]);  acc[5]  = fmaf(x, w1.y, acc[5]);
      acc[6]  = fmaf(x, w1.z, acc[6]);  acc[7]  = fmaf(x, w1.w, acc[7]);
      acc[8]  = fmaf(x, w2.x, acc[8]);  acc[9]  = fmaf(x, w2.y, acc[9]);
      acc[10] = fmaf(x, w2.z, acc[10]); acc[11] = fmaf(x, w2.w, acc[11]);
      acc[12] = fmaf(x, w3.x, acc[12]); acc[13] = fmaf(x, w3.y, acc[13]);
      acc[14] = fmaf(x, w3.z, acc[14]); acc[15] = fmaf(x, w3.w, acc[15]);
      acc[16] = fmaf(x, w4.x, acc[16]); acc[17] = fmaf(x, w4.y, acc[17]);
      acc[18] = fmaf(x, w4.z, acc[18]); acc[19] = fmaf(x, w4.w, acc[19]);
    }
  }

  __syncthreads();
  float* red = xs;  // 4*64*20 = 5120 floats scratch
#pragma unroll
  for (int d = 0; d < 20; ++d) red[wave * 1280 + lane * 20 + d] = acc[d];
  __syncthreads();
#pragma unroll
  for (int r = 0; r < 5; ++r) {
    int f = r * 256 + tid;
    float s = (red[f] + red[1280 + f]) + (red[2560 + f] + red[3840 + f]);
    O[f] = s + bv[f % 20];
  }
}

// LDS-weight TreeLSTM eval of one (pair, dim) unit — init pass only.
#define EVAL_UNIT(A_, B2_, PS_, DD_, HN_)                                     \
  {                                                                           \
    float ai = bcs[DD_], af = bcs[20 + DD_], ag = bcs[40 + DD_],              \
          au = bcs[60 + DD_], ao = bcs[80 + DD_];                             \
    const int xa_ = (A_)*20, xb_ = (B2_)*20, wr_ = (DD_)*44;                  \
    _Pragma("unroll")                                                         \
    for (int kq = 0; kq < 10; ++kq) {                                         \
      const float4 xq = (kq < 5)                                              \
          ? *(const float4*)(h_state + xa_ + kq * 4)                          \
          : *(const float4*)(h_state + xb_ + (kq - 5) * 4);                   \
      const float4 wi = *(const float4*)(Wt + wr_ + kq * 4);                  \
      const float4 wf = *(const float4*)(Wt + 880  + wr_ + kq * 4);           \
      const float4 wg = *(const float4*)(Wt + 1760 + wr_ + kq * 4);           \
      const float4 wu = *(const float4*)(Wt + 2640 + wr_ + kq * 4);           \
      const float4 wo = *(const float4*)(Wt + 3520 + wr_ + kq * 4);           \
      ai = fmaf(xq.x, wi.x, ai); ai = fmaf(xq.y, wi.y, ai);                   \
      ai = fmaf(xq.z, wi.z, ai); ai = fmaf(xq.w, wi.w, ai);                   \
      af = fmaf(xq.x, wf.x, af); af = fmaf(xq.y, wf.y, af);                   \
      af = fmaf(xq.z, wf.z, af); af = fmaf(xq.w, wf.w, af);                   \
      ag = fmaf(xq.x, wg.x, ag); ag = fmaf(xq.y, wg.y, ag);                   \
      ag = fmaf(xq.z, wg.z, ag); ag = fmaf(xq.w, wg.w, ag);                   \
      au = fmaf(xq.x, wu.x, au); au = fmaf(xq.y, wu.y, au);                   \
      au = fmaf(xq.z, wu.z, au); au = fmaf(xq.w, wu.w, au);                   \
      ao = fmaf(xq.x, wo.x, ao); ao = fmaf(xq.y, wo.y, ao);                   \
      ao = fmaf(xq.z, wo.z, ao); ao = fmaf(xq.w, wo.w, ao);                   \
    }                                                                         \
    const float cl_ = c_state[(A_)*20 + (DD_)],                               \
                cr_ = c_state[(B2_)*20 + (DD_)];                              \
    const float cn_ = cl_ * fsig(af + 1.0f) + cr_ * fsig(ag + 1.0f) +         \
                      ftanhf(au) * fsig(ai);                                  \
    (HN_) = fsig(ao) * ftanhf(cn_);                                           \
    nh[(PS_)*20 + (DD_)] = (HN_);                                             \
    nc[(PS_)*20 + (DD_)] = cn_;                                               \
  }

// ---------------------------------------------------------------------------
// Phase 2 (R12, best known): per-row Gumbel tree pyramid, ONE WAVE per row.
// Column-split eval (lane owns output cols {2l, 2l+1}; full-K dots, no
// cross-lane gate combine); hoisted eval LDS reads; DPP argmax/shift;
// 2-deep U prefetch; merge-bypass via nh/nc.
// ---------------------------------------------------------------------------
__global__ __launch_bounds__(64, 1)
void pyramid_kernel(const float* __restrict__ H0, const float* __restrict__ C0,
                    const float* __restrict__ Wc, const float* __restrict__ bcg,
                    const float* __restrict__ query, const float* __restrict__ U,
                    const int* __restrict__ length, float* __restrict__ out) {
  __shared__ float h_state[64 * 20];
  __shared__ float c_state[64 * 20];
  __shared__ float nh[63 * 20];     // cached pair h_new, by pair SLOT
  __shared__ float nc[63 * 20];     // cached pair c_new
  __shared__ float Wt[100 * 44];    // transposed W_comp (init only)
  __shared__ float bcs[100];        // bias (init only)
  __shared__ float qvs[20];         // query (init only)
  __shared__ float sc[200];         // gate-sum scratch: [pair][100]

  const int b    = blockIdx.x;
  const int lane = threadIdx.x;     // one wave
  const int p    = lane >> 5;       // nonlin phase: pair select
  const int dd   = lane & 31;       // nonlin phase: output dim (<20 active)
  const int ddc  = dd < 20 ? dd : 19;
  int len = length[b];
  len = len < 1 ? 1 : (len > 64 ? 64 : len);

  // ---- stage ----
  {
    const float4* h4 = (const float4*)(H0 + (size_t)b * kRowElems);
    const float4* c4 = (const float4*)(C0 + (size_t)b * kRowElems);
#pragma unroll
    for (int r = 0; r < 5; ++r) {
      int f = r * 64 + lane;  // 320 float4 per array
      ((float4*)h_state)[f] = h4[f];
      ((float4*)c_state)[f] = c4[f];
    }
  }
  for (int f = lane; f < 4000; f += 64) {
    int c = f / 40, k = f - c * 40;
    Wt[c * 44 + k] = Wc[k * 100 + c];
  }
  for (int f = lane; f < 100; f += 64) bcs[f] = bcg[f];
  if (lane < 20) qvs[lane] = query[lane];

  // ---- loop weights: output-column split, straight from global ----
  const bool cact = lane < 50;
  const int  c0   = cact ? 2 * lane : 0;
  const int  c1   = c0 + 1;
  v2f Wv0[20], Wv1[20];   // [k2] = {W[2k2][c], W[2k2+1][c]}
#pragma unroll
  for (int k2 = 0; k2 < 20; ++k2) {
    Wv0[k2] = (v2f){Wc[(2 * k2) * 100 + c0], Wc[(2 * k2 + 1) * 100 + c0]};
    Wv1[k2] = (v2f){Wc[(2 * k2) * 100 + c1], Wc[(2 * k2 + 1) * 100 + c1]};
  }
  const float bb0 = bcg[c0], bb1 = bcg[c1];
  const float qv_r = query[ddc];

  // per-lane register bookkeeping (position-indexed)
  int   idx_r  = lane;
  int   pidx_r = lane;
  float lgt_r  = -FLT_MAX;

  const int col = lane < 62 ? lane : 62;
  const float u_row0 = U[b * kLM1 + col];
  float u_c = U[(size_t)1 * (kB * kLM1) + b * kLM1 + col];

  // ---- init: evaluate all 63 adjacent pairs (LDS weights, parallel) ----
#pragma unroll 1
  for (int r = 0; r < 20; ++r) {
    int uu = r * 64 + lane;
    if (uu < 1260) {
      int pp = uu / 20, d2 = uu - pp * 20;
      float hn_;
      EVAL_UNIT(pp, pp + 1, pp, d2, hn_);
      (void)hn_;
    }
  }
  if (lane < 63) {
    float s = 0.0f;
#pragma unroll
    for (int q = 0; q < 5; ++q) {
      const float4 t  = *(const float4*)(nh  + lane * 20 + q * 4);
      const float4 qv = *(const float4*)(qvs + q * 4);
      s = fmaf(t.x, qv.x, s); s = fmaf(t.y, qv.y, s);
      s = fmaf(t.z, qv.z, s); s = fmaf(t.w, qv.w, s);
    }
    lgt_r = s;
  }

  float gcur = -__logf(-__logf(u_row0 + 1e-20f) + 1e-20f);

  const int nIter = len - 1;
#pragma unroll 1
  for (int i = 0; i < nIter; ++i) {
    const int n = kL - i;  // current sequence length

    // ---- argmax via u32 sort-key + DPP (ties -> lowest index) ----
    const float zf = lgt_r + gcur;
    const unsigned ub = __float_as_uint(zf);
    unsigned key = ((int)ub < 0) ? ~ub : (ub | 0x80000000u);
    const bool valid = (lane <= n - 2) && ((i + 1 + lane) < len);
    if (!valid) key = 0u;
    unsigned m = key;
    UMAX_STAGE(0xB1);
    UMAX_STAGE(0x4E);
    UMAX_STAGE(0x141);
    UMAX_STAGE(0x140);
    UMAX_STAGE(0x142);
    UMAX_STAGE(0x143);
    const unsigned gmax = (unsigned)rdl_i((int)m, 63);
    const unsigned long long bal = __ballot(valid && (key == gmax));
    const int k = (int)(__ffsll(bal) - 1);  // wave-uniform

    // ---- issue U load for row i+2 (2-deep pipeline) ----
    float u_d = 0.0f;
    if (i + 2 <= kLM1 - 1) u_d = U[(size_t)(i + 2) * (kB * kLM1) + b * kLM1 + col];

    // ---- pre-shift lookups via readlane ----
    const int km1 = (k >= 1) ? k - 1 : 0;
    const int kp2 = (k <= n - 3) ? k + 2 : 0;
    const int tgt = rdl_i(idx_r,  k);
    const int psk = rdl_i(pidx_r, k);
    const int iA  = rdl_i(idx_r,  km1);
    const int pA  = rdl_i(pidx_r, km1);
    const int iB  = rdl_i(idx_r,  kp2);

    // ---- HOISTED eval reads (latency overlaps the VALU work below) ----
    v2f hA2[10], hT2[10], hB2[10];
#pragma unroll
    for (int q = 0; q < 5; ++q) {
      const float4 tA = *(const float4*)(h_state + iA * 20 + q * 4);
      const float4 tT = *(const float4*)(nh + psk * 20 + q * 4);
      const float4 tB = *(const float4*)(h_state + iB * 20 + q * 4);
      hA2[2*q]   = (v2f){tA.x, tA.y};  hA2[2*q+1] = (v2f){tA.z, tA.w};
      hT2[2*q]   = (v2f){tT.x, tT.y};  hT2[2*q+1] = (v2f){tT.z, tT.w};
      hB2[2*q]   = (v2f){tB.x, tB.y};  hB2[2*q+1] = (v2f){tB.z, tB.w};
    }
    const float cA_ = c_state[iA * 20 + ddc];   // pair A left c
    const float cT_ = nc[psk * 20 + ddc];       // merged node c
    const float cB_ = c_state[iB * 20 + ddc];   // pair B right c

    // ---- merge: winner's cached (h,c) -> state slot tgt (off-chain) ----
    if (lane < 20) {
      h_state[tgt * 20 + lane] = nh[psk * 20 + lane];
      c_state[tgt * 20 + lane] = nc[psk * 20 + lane];
    }

    // ---- shift position-indexed registers via DPP row_shl:1 ----
    {
      int   sI = DPPI(idx_r,  0x101);
      int   sP = DPPI(pidx_r, 0x101);
      float sL = DPPF(lgt_r,  0x101);
      const int   bi16 = rdl_i(idx_r, 16),  bi32 = rdl_i(idx_r, 32),
                  bi48 = rdl_i(idx_r, 48);
      const int   bp16 = rdl_i(pidx_r, 16), bp32 = rdl_i(pidx_r, 32),
                  bp48 = rdl_i(pidx_r, 48);
      const float bl16 = rdl_f(lgt_r, 16),  bl32 = rdl_f(lgt_r, 32),
                  bl48 = rdl_f(lgt_r, 48);
      if (lane == 15) { sI = bi16; sP = bp16; sL = bl16; }
      if (lane == 31) { sI = bi32; sP = bp32; sL = bl32; }
      if (lane == 47) { sI = bi48; sP = bp48; sL = bl48; }
      const bool doI = (lane >= k + 1) && (lane <= n - 2);
      const bool doP = (lane >= k + 1) && (lane <= n - 3);
      if (doI) idx_r = sI;
      if (doP) { pidx_r = sP; lgt_r = sL; }
    }

    // ---- evaluate both candidate pairs: column-split full-K dots ----
    if (i < len - 2) {
      const bool hasA = (k >= 1);
      const bool hasB = (k <= n - 3);

      // pair A x = [hA | hT], pair B x = [hT | hB]; 4 indep chains
      v2f aA0 = (v2f){0.f, 0.f}, aA1 = aA0, aB0 = aA0, aB1 = aA0;
#pragma unroll
      for (int k2 = 0; k2 < 10; ++k2) {
        PKFMA(aA0, hA2[k2], Wv0[k2]);
        PKFMA(aA1, hA2[k2], Wv1[k2]);
        PKFMA(aB0, hT2[k2], Wv0[k2]);
        PKFMA(aB1, hT2[k2], Wv1[k2]);
      }
#pragma unroll
      for (int k2 = 10; k2 < 20; ++k2) {
        PKFMA(aA0, hT2[k2 - 10], Wv0[k2]);
        PKFMA(aA1, hT2[k2 - 10], Wv1[k2]);
        PKFMA(aB0, hB2[k2 - 10], Wv0[k2]);
        PKFMA(aB1, hB2[k2 - 10], Wv1[k2]);
      }

      // gate sums (+bias) -> LDS scratch
      if (cact) {
        *(v2f*)(sc + c0)       = (v2f){aA0[0] + aA0[1] + bb0,
                                       aA1[0] + aA1[1] + bb1};
        *(v2f*)(sc + 100 + c0) = (v2f){aB0[0] + aB0[1] + bb0,
                                       aB1[0] + aB1[1] + bb1};
      }

      // nonlinearities: lanes (p, dd<20); pair A on half0, pair B on half1
      const float* scp = sc + p * 100;
      const float i_ = scp[ddc],      fl_ = scp[20 + ddc],
                  fr_ = scp[40 + ddc], u_ = scp[60 + ddc],
                  o_ = scp[80 + ddc];
      const float cl_ = (p == 0) ? cA_ : cT_;
      const float cr_ = (p == 0) ? cT_ : cB_;
      const float cn_ = cl_ * fsig(fl_ + 1.0f) + cr_ * fsig(fr_ + 1.0f) +
                        ftanhf(u_) * fsig(i_);
      const float hn_ = fsig(o_) * ftanhf(cn_);
      const int   slot = (p == 0) ? pA : psk;
      const bool  mine = (p == 0) ? hasA : hasB;
      if (mine && dd < 20) {
        nh[slot * 20 + dd] = hn_;
        nc[slot * 20 + dd] = cn_;
      }
      float pr = (dd < 20) ? hn_ * qv_r : 0.0f;
      LOGIT_REDUCE(pr);
      const float vA = rdl_f(pr, 31);
      const float vB = rdl_f(pr, 63);
      if (hasA && lane == k - 1) lgt_r = vA;
      if (hasB && lane == k)     lgt_r = vB;
    }

    // ---- gumbel transform for row i+1 (loaded >=1 iteration ago) ----
    gcur = -__logf(-__logf(u_c + 1e-20f) + 1e-20f);
    u_c  = u_d;
  }

  const int root = rdl_i(idx_r, 0);
  if (lane < 20) {
    out[b * 20 + lane] = h_state[root * 20 + lane];
  }
}

}  // namespace

extern "C" void kernel_launch(void* const* d_in, const int* in_sizes, int n_in,
                              void* d_out, int out_size, void* d_ws, size_t ws_size,
                              hipStream_t stream) {
  const float* input_h  = (const float*)d_in[0];
  const float* input_c  = (const float*)d_in[1];
  const float* W_reduce = (const float*)d_in[2];
  const float* b_reduce = (const float*)d_in[3];
  const float* W_comp   = (const float*)d_in[4];
  const float* b_comp   = (const float*)d_in[5];
  const float* query    = (const float*)d_in[6];
  const float* u_noise  = (const float*)d_in[7];
  const int*   length   = (const int*)d_in[8];
  float* out = (float*)d_out;

  float* H0 = (float*)d_ws;
  float* C0 = H0 + (size_t)kB * kL * kLow;

  reduce_kernel<<<dim3(2 * kB), dim3(256), 0, stream>>>(
      input_h, input_c, W_reduce, b_reduce, H0, C0);
  pyramid_kernel<<<dim3(kB), dim3(64), 0, stream>>>(
      H0, C0, W_comp, b_comp, query, u_noise, length, out);
}